// Round 1
// baseline (350.577 us; speedup 1.0000x reference)
//
#include <hip/hip_runtime.h>

// Problem constants (TextEncoder_55671366091616)
#define BB 32
#define SS 2048
#define DD 1024
#define EE 64
#define KK 8
#define TT 128   // N_TAGS

// ---------------------------------------------------------------------------
// Kernel A: gather + masked mean-pool per (b,e) entity, write ent_emb to ws.
// Also initializes d_out with the bias (so kernel B can atomicAdd partials).
// grid = B*E = 2048 blocks, 256 threads. Each thread owns 4 contiguous cols
// (float4): fully coalesced 4 KB row reads.
// ---------------------------------------------------------------------------
__global__ __launch_bounds__(256) void pool_kernel(
    const float* __restrict__ hs,       // [B,S,D]
    const int*   __restrict__ subw_idx, // [B,E,K]
    const int*   __restrict__ subw_cnt, // [B,E]
    const int*   __restrict__ num_ent,  // [B]
    const float* __restrict__ fc_b,     // [T]
    float*       __restrict__ ent,      // ws: [B*E, D]
    float*       __restrict__ out)      // [B*E, T]
{
    const int be = blockIdx.x;
    const int b  = be >> 6;   // / EE
    const int e  = be & 63;
    const int t  = threadIdx.x;

    const int cnt = subw_cnt[be];          // block-uniform (scalar load)
    const int ne  = num_ent[b];
    const float scale = (e < ne) ? (1.0f / (float)cnt) : 0.0f;

    const int* idxp = subw_idx + (size_t)be * KK;

    float4 acc = make_float4(0.f, 0.f, 0.f, 0.f);
    #pragma unroll
    for (int k = 0; k < KK; ++k) {
        if (k < cnt) {                      // block-uniform branch
            const int s = idxp[k];          // scalar load
            const float4* row = (const float4*)(hs + ((size_t)b * SS + s) * DD);
            float4 v = row[t];
            acc.x += v.x; acc.y += v.y; acc.z += v.z; acc.w += v.w;
        }
    }
    acc.x *= scale; acc.y *= scale; acc.z *= scale; acc.w *= scale;
    ((float4*)(ent + (size_t)be * DD))[t] = acc;

    // Bias-init the output (re-poisoned 0xAA before every timed call).
    // B*E*T = 262144 elems; grid has 524288 threads.
    const int gid = be * 256 + t;
    if (gid < BB * EE * TT) {
        out[gid] = fc_b[gid & (TT - 1)];
    }
}

// ---------------------------------------------------------------------------
// Kernel B: fp32 GEMM  out[M=2048, T=128] += ent[M,D] * fc_w[T,D]^T
// Tiles: M_TILE=16 rows x full 128 tags, split-K=4 (chunks of 256).
// grid = (2048/16)*4 = 512 blocks, 256 threads.
// Thread t -> tag n = t&127, m-group mg = t>>7 owning 8 rows.
// W tile in LDS padded [128][33]: read bank = (n+kk)%32 -> 2-way only (free).
// A tile reads are wave-uniform broadcasts.
// ---------------------------------------------------------------------------
#define M_TILE 16
#define KSPLIT 4
#define KCH   (DD / KSPLIT)   // 256
#define KSUB  32

__global__ __launch_bounds__(256) void fc_kernel(
    const float* __restrict__ ent,   // [B*E, D]
    const float* __restrict__ fc_w,  // [T, D]
    float*       __restrict__ out)   // [B*E, T]
{
    __shared__ float Al[M_TILE][KSUB];
    __shared__ float Wl[TT][KSUB + 1];

    const int bx    = blockIdx.x;
    const int mtile = bx >> 2;           // / KSPLIT
    const int ks    = bx & (KSPLIT - 1);
    const int t     = threadIdx.x;
    const int n     = t & (TT - 1);
    const int m0    = (t >> 7) * 8;

    const int k0 = ks * KCH;

    float acc[8] = {0.f, 0.f, 0.f, 0.f, 0.f, 0.f, 0.f, 0.f};

    for (int kc = 0; kc < KCH; kc += KSUB) {
        const int kbase = k0 + kc;

        // Stage A tile: 16x32 = 512 floats, 2 per thread, coalesced.
        #pragma unroll
        for (int i = t; i < M_TILE * KSUB; i += 256) {
            const int mm = i >> 5, kk = i & 31;
            Al[mm][kk] = ent[(size_t)(mtile * M_TILE + mm) * DD + kbase + kk];
        }
        // Stage W tile: 128x32 = 4096 floats, float4 x4 per thread.
        #pragma unroll
        for (int i = t * 4; i < TT * KSUB; i += 256 * 4) {
            const int tag = i >> 5, kk = i & 31;
            float4 w = *(const float4*)(fc_w + (size_t)tag * DD + kbase + kk);
            Wl[tag][kk + 0] = w.x;
            Wl[tag][kk + 1] = w.y;
            Wl[tag][kk + 2] = w.z;
            Wl[tag][kk + 3] = w.w;
        }
        __syncthreads();

        #pragma unroll
        for (int kk = 0; kk < KSUB; ++kk) {
            const float w = Wl[n][kk];
            #pragma unroll
            for (int m = 0; m < 8; ++m)
                acc[m] += Al[m0 + m][kk] * w;
        }
        __syncthreads();
    }

    #pragma unroll
    for (int m = 0; m < 8; ++m)
        atomicAdd(&out[(size_t)(mtile * M_TILE + m0 + m) * TT + n], acc[m]);
}

extern "C" void kernel_launch(void* const* d_in, const int* in_sizes, int n_in,
                              void* d_out, int out_size, void* d_ws, size_t ws_size,
                              hipStream_t stream) {
    const float* hs       = (const float*)d_in[0];
    const int*   subw_idx = (const int*)  d_in[1];
    const int*   subw_cnt = (const int*)  d_in[2];
    const int*   num_ent  = (const int*)  d_in[3];
    const float* fc_w     = (const float*)d_in[4];
    const float* fc_b     = (const float*)d_in[5];
    float*       out      = (float*)d_out;
    float*       ent      = (float*)d_ws;  // needs B*E*D*4 = 8 MB of scratch

    pool_kernel<<<BB * EE, 256, 0, stream>>>(hs, subw_idx, subw_cnt, num_ent,
                                             fc_b, ent, out);
    fc_kernel<<<(BB * EE / M_TILE) * KSPLIT, 256, 0, stream>>>(ent, fc_w, out);
}

// Round 2
// 318.429 us; speedup vs baseline: 1.1010x; 1.1010x over previous
//
#include <hip/hip_runtime.h>

// Problem constants (TextEncoder_55671366091616)
#define BB 32
#define SS 2048
#define DD 1024
#define EE 64
#define KK 8
#define TT 128            // N_TAGS
#define MM (BB * EE)      // 2048 output rows

// Split-K for the MFMA FC
#define KSPLIT 8
#define KCHUNK (DD / KSPLIT)   // 128
#define MT 32                  // M rows per block

typedef __attribute__((ext_vector_type(8))) short short8;   // bf16x8 frag (4 VGPRs)
typedef __attribute__((ext_vector_type(4))) float f32x4;    // MFMA accumulator

// fp32 -> bf16 round-to-nearest-even
__device__ __forceinline__ unsigned short f2bf(float f) {
    union { float f; unsigned int u; } v; v.f = f;
    unsigned int u = v.u + 0x7FFFu + ((v.u >> 16) & 1u);
    return (unsigned short)(u >> 16);
}

// ---------------------------------------------------------------------------
// Kernel A: gather + masked mean-pool per (b,e) -> ent_bf16 [M, D] in ws.
// Also converts fc_w (fp32 [T,D]) to bf16 into ws (64 elems per block).
// grid = 2048 blocks x 256 threads; each thread owns 4 contiguous cols.
// ---------------------------------------------------------------------------
__global__ __launch_bounds__(256) void pool_kernel(
    const float* __restrict__ hs,        // [B,S,D]
    const int*   __restrict__ subw_idx,  // [B,E,K]
    const int*   __restrict__ subw_cnt,  // [B,E]
    const int*   __restrict__ num_ent,   // [B]
    const float* __restrict__ fc_w,      // [T,D]
    unsigned short* __restrict__ entb,   // ws: [M, D] bf16
    unsigned short* __restrict__ wb)     // ws: [T, D] bf16
{
    const int be = blockIdx.x;
    const int b  = be >> 6;
    const int e  = be & 63;
    const int t  = threadIdx.x;

    const int cnt = subw_cnt[be];                 // block-uniform
    const int ne  = num_ent[b];
    const float scale = (e < ne) ? (1.0f / (float)cnt) : 0.0f;

    const int* idxp = subw_idx + (size_t)be * KK;

    float4 acc = make_float4(0.f, 0.f, 0.f, 0.f);
    #pragma unroll
    for (int k = 0; k < KK; ++k) {
        if (k < cnt) {                            // block-uniform branch
            const int s = idxp[k];
            const float4* row = (const float4*)(hs + ((size_t)b * SS + s) * DD);
            float4 v = row[t];
            acc.x += v.x; acc.y += v.y; acc.z += v.z; acc.w += v.w;
        }
    }
    ushort4 o;
    o.x = f2bf(acc.x * scale); o.y = f2bf(acc.y * scale);
    o.z = f2bf(acc.z * scale); o.w = f2bf(acc.w * scale);
    *(ushort4*)(entb + (size_t)be * DD + 4 * t) = o;   // 8 B store, aligned

    // Convert 64 fc_w elems per block: total 2048*64 = 131072 = T*D.
    if (t < 64) {
        const int j = be * 64 + t;
        wb[j] = f2bf(fc_w[j]);
    }
}

// ---------------------------------------------------------------------------
// Kernel B: bf16 MFMA GEMM partials.  part[s][m][n] = ent[m, ks] . W[n, ks]
// grid = (M/MT) * KSPLIT = 64*8 = 512 blocks, 256 threads (4 waves).
// Block tile: 32 M x 128 N x 128 K.  Wave w: M-sub (w&1), N-base (w>>1)*64.
// 16x16x32 bf16 MFMA; frag layout per verified m89 mapping.
// ---------------------------------------------------------------------------
__global__ __launch_bounds__(256) void fc_mfma_kernel(
    const unsigned short* __restrict__ entb, // [M,D] bf16
    const unsigned short* __restrict__ wb,   // [T,D] bf16
    float* __restrict__ part)                // [KSPLIT, M, T] f32
{
    __shared__ unsigned short As[MT][32];     // 2 KB
    __shared__ unsigned short Bs[TT][32];     // 8 KB

    const int bx = blockIdx.x;
    const int mt = bx >> 3;              // 0..63
    const int ks = bx & (KSPLIT - 1);    // 0..7
    const int t  = threadIdx.x;
    const int wid  = t >> 6;
    const int lane = t & 63;

    const int msub  = (wid & 1) * 16;    // wave's M offset within tile
    const int nbase = (wid >> 1) * 64;   // wave's N offset (4 subtiles of 16)

    const int k0 = ks * KCHUNK;

    f32x4 acc0 = {0.f,0.f,0.f,0.f}, acc1 = {0.f,0.f,0.f,0.f};
    f32x4 acc2 = {0.f,0.f,0.f,0.f}, acc3 = {0.f,0.f,0.f,0.f};

    const int lm = lane & 15;            // frag row index
    const int lq = (lane >> 4) * 8;      // frag k offset

    for (int kc = 0; kc < KCHUNK; kc += 32) {
        // Stage A: 32 rows x 32 bf16 = 2 KB. threads 0..127, 16 B each.
        if (t < 128) {
            const int m = t >> 2, s = t & 3;
            *(float4*)&As[m][s * 8] =
                *(const float4*)(entb + (size_t)(mt * MT + m) * DD + k0 + kc + s * 8);
        }
        // Stage B: 128 rows x 32 bf16 = 8 KB. 256 threads x 2, 16 B each.
        #pragma unroll
        for (int j = 0; j < 2; ++j) {
            const int i = t + j * 256;
            const int n = i >> 2, s = i & 3;
            *(float4*)&Bs[n][s * 8] =
                *(const float4*)(wb + (size_t)n * DD + k0 + kc + s * 8);
        }
        __syncthreads();

        short8 a = *(const short8*)&As[msub + lm][lq];
        short8 b0 = *(const short8*)&Bs[nbase +  0 + lm][lq];
        short8 b1 = *(const short8*)&Bs[nbase + 16 + lm][lq];
        short8 b2 = *(const short8*)&Bs[nbase + 32 + lm][lq];
        short8 b3 = *(const short8*)&Bs[nbase + 48 + lm][lq];

        acc0 = __builtin_amdgcn_mfma_f32_16x16x32_bf16(a, b0, acc0, 0, 0, 0);
        acc1 = __builtin_amdgcn_mfma_f32_16x16x32_bf16(a, b1, acc1, 0, 0, 0);
        acc2 = __builtin_amdgcn_mfma_f32_16x16x32_bf16(a, b2, acc2, 0, 0, 0);
        acc3 = __builtin_amdgcn_mfma_f32_16x16x32_bf16(a, b3, acc3, 0, 0, 0);
        __syncthreads();
    }

    // D layout: lane holds D[row = (lane>>4)*4 + r][col = lane&15]
    float* outp = part + (size_t)ks * MM * TT;
    const int mrow = mt * MT + msub + (lane >> 4) * 4;
    const int ncol = nbase + (lane & 15);
    #pragma unroll
    for (int r = 0; r < 4; ++r) {
        const size_t base = (size_t)(mrow + r) * TT + ncol;
        outp[base +  0] = acc0[r];
        outp[base + 16] = acc1[r];
        outp[base + 32] = acc2[r];
        outp[base + 48] = acc3[r];
    }
}

// ---------------------------------------------------------------------------
// Kernel C: reduce split-K partials + bias -> out.  float4 per thread.
// grid = (M*T/4)/256 = 256 blocks.
// ---------------------------------------------------------------------------
__global__ __launch_bounds__(256) void reduce_kernel(
    const float* __restrict__ part,  // [KSPLIT, M*T]
    const float* __restrict__ fc_b,  // [T]
    float* __restrict__ out)         // [M*T]
{
    const int i = blockIdx.x * 256 + threadIdx.x;   // float4 index
    float4 s = *(const float4*)(fc_b + (i & 31) * 4);
    #pragma unroll
    for (int k = 0; k < KSPLIT; ++k) {
        float4 p = *(const float4*)(part + (size_t)k * MM * TT + 4 * i);
        s.x += p.x; s.y += p.y; s.z += p.z; s.w += p.w;
    }
    *(float4*)(out + 4 * (size_t)i) = s;
}

extern "C" void kernel_launch(void* const* d_in, const int* in_sizes, int n_in,
                              void* d_out, int out_size, void* d_ws, size_t ws_size,
                              hipStream_t stream) {
    const float* hs       = (const float*)d_in[0];
    const int*   subw_idx = (const int*)  d_in[1];
    const int*   subw_cnt = (const int*)  d_in[2];
    const int*   num_ent  = (const int*)  d_in[3];
    const float* fc_w     = (const float*)d_in[4];
    const float* fc_b     = (const float*)d_in[5];
    float*       out      = (float*)d_out;

    // ws layout (16B-aligned): entb 4 MB | wb 256 KB | partials 8 MB
    unsigned short* entb = (unsigned short*)d_ws;
    unsigned short* wb   = (unsigned short*)((char*)d_ws + (size_t)MM * DD * 2);
    float*          part = (float*)((char*)d_ws + (size_t)MM * DD * 2 + (size_t)TT * DD * 2);

    pool_kernel<<<MM, 256, 0, stream>>>(hs, subw_idx, subw_cnt, num_ent,
                                        fc_w, entb, wb);
    fc_mfma_kernel<<<(MM / MT) * KSPLIT, 256, 0, stream>>>(entb, wb, part);
    reduce_kernel<<<(MM * TT / 4) / 256, 256, 0, stream>>>(part, fc_b, out);
}

// Round 3
// 318.179 us; speedup vs baseline: 1.1018x; 1.0008x over previous
//
#include <hip/hip_runtime.h>

// Problem constants (TextEncoder_55671366091616)
#define BB 32
#define SS 2048
#define DD 1024
#define EE 64
#define KK 8
#define TT 128            // N_TAGS
#define MM (BB * EE)      // 2048 output rows

#define KSPLIT 8
#define KCHUNK (DD / KSPLIT)   // 128
#define MT 32                  // M rows per block
#define LSTR 136               // LDS row stride in bf16 (272 B = 68 dw -> +4 banks/row)

typedef __attribute__((ext_vector_type(8))) short short8;   // bf16x8 frag
typedef __attribute__((ext_vector_type(4))) float f32x4;    // MFMA accumulator

__device__ __forceinline__ unsigned short f2bf(float f) {
    union { float f; unsigned int u; } v; v.f = f;
    unsigned int u = v.u + 0x7FFFu + ((v.u >> 16) & 1u);
    return (unsigned short)(u >> 16);
}

// ---------------------------------------------------------------------------
// Fused gather+pool+GEMM partials.
// grid = (M/MT) * KSPLIT = 64*8 = 512 blocks, 256 threads (4 waves).
// Block (mt, ks): rows [mt*32, mt*32+32), K columns [ks*128, ks*128+128).
//  Stage A: pool 32 entities' 128-col chunks on the fly (fp32 acc -> bf16).
//  Stage B: convert W fp32 chunk [128 x 128] -> bf16 LDS (L2-resident reads).
//  MFMA:    16x16x32 bf16, wave w: M-sub (w&1)*16, N-base (w>>1)*64,
//           4 k-steps x 4 n-subtiles = 16 MFMAs.
// LDS rows padded to 136 bf16: b128 frag loads are 2-way max (free).
// ---------------------------------------------------------------------------
__global__ __launch_bounds__(256) void fc_fused_kernel(
    const float* __restrict__ hs,        // [B,S,D]
    const int*   __restrict__ subw_idx,  // [B,E,K]
    const int*   __restrict__ subw_cnt,  // [B,E]
    const int*   __restrict__ num_ent,   // [B]
    const float* __restrict__ fc_w,      // [T,D]
    float* __restrict__ part)            // [KSPLIT, M, T] f32
{
    __shared__ unsigned short As[MT][LSTR];   // 8.5 KB
    __shared__ unsigned short Bs[TT][LSTR];   // 34 KB

    const int bx = blockIdx.x;
    const int mt = bx >> 3;              // 0..63
    const int ks = bx & (KSPLIT - 1);    // 0..7
    const int t  = threadIdx.x;
    const int wid  = t >> 6;
    const int lane = t & 63;
    const int k0 = ks * KCHUNK;

    // ---- Stage A: gather + mean-pool. 8 threads per row, 16 cols each. ----
    {
        const int r   = t >> 3;          // 0..31  entity row within tile
        const int sub = t & 7;           // 0..7   16-col slice
        const int be  = mt * MT + r;
        const int b   = be >> 6;
        const int e   = be & 63;
        const int cnt = subw_cnt[be];
        const int ne  = num_ent[b];
        const float scale = (e < ne) ? (1.0f / (float)cnt) : 0.0f;
        const int* idxp = subw_idx + (size_t)be * KK;

        float acc[16];
        #pragma unroll
        for (int j = 0; j < 16; ++j) acc[j] = 0.f;

        for (int k = 0; k < cnt; ++k) {
            const int s = idxp[k];
            const float4* p = (const float4*)(hs + ((size_t)b * SS + s) * DD
                                              + k0 + sub * 16);
            #pragma unroll
            for (int j = 0; j < 4; ++j) {
                float4 v = p[j];
                acc[4*j+0] += v.x; acc[4*j+1] += v.y;
                acc[4*j+2] += v.z; acc[4*j+3] += v.w;
            }
        }
        ushort4 o[4];
        #pragma unroll
        for (int j = 0; j < 4; ++j) {
            o[j].x = f2bf(acc[4*j+0] * scale);
            o[j].y = f2bf(acc[4*j+1] * scale);
            o[j].z = f2bf(acc[4*j+2] * scale);
            o[j].w = f2bf(acc[4*j+3] * scale);
        }
        // 16 bf16 = 32 B -> two 16-B stores (row base 272 B, 16-B aligned)
        *(ushort4*)&As[r][sub * 16 + 0]  = o[0];
        *(ushort4*)&As[r][sub * 16 + 4]  = o[1];
        *(ushort4*)&As[r][sub * 16 + 8]  = o[2];
        *(ushort4*)&As[r][sub * 16 + 12] = o[3];
    }

    // ---- Stage B: W fp32 -> bf16. 2 threads per tag row, 64 cols each. ----
    {
        const int n = t >> 1;            // 0..127 tag row
        const int h = (t & 1) * 64;      // col half
        const float4* wrow = (const float4*)(fc_w + (size_t)n * DD + k0 + h);
        #pragma unroll
        for (int j = 0; j < 16; ++j) {
            float4 v = wrow[j];
            ushort4 o;
            o.x = f2bf(v.x); o.y = f2bf(v.y); o.z = f2bf(v.z); o.w = f2bf(v.w);
            *(ushort4*)&Bs[n][h + j * 4] = o;
        }
    }
    __syncthreads();

    // ---- MFMA phase ----
    const int msub  = (wid & 1) * 16;
    const int nbase = (wid >> 1) * 64;
    const int lm = lane & 15;
    const int lq = (lane >> 4) * 8;

    f32x4 acc0 = {0.f,0.f,0.f,0.f}, acc1 = {0.f,0.f,0.f,0.f};
    f32x4 acc2 = {0.f,0.f,0.f,0.f}, acc3 = {0.f,0.f,0.f,0.f};

    #pragma unroll
    for (int kstep = 0; kstep < KCHUNK / 32; ++kstep) {
        const int kc = kstep * 32 + lq;
        short8 a  = *(const short8*)&As[msub + lm][kc];
        short8 b0 = *(const short8*)&Bs[nbase +  0 + lm][kc];
        short8 b1 = *(const short8*)&Bs[nbase + 16 + lm][kc];
        short8 b2 = *(const short8*)&Bs[nbase + 32 + lm][kc];
        short8 b3 = *(const short8*)&Bs[nbase + 48 + lm][kc];
        acc0 = __builtin_amdgcn_mfma_f32_16x16x32_bf16(a, b0, acc0, 0, 0, 0);
        acc1 = __builtin_amdgcn_mfma_f32_16x16x32_bf16(a, b1, acc1, 0, 0, 0);
        acc2 = __builtin_amdgcn_mfma_f32_16x16x32_bf16(a, b2, acc2, 0, 0, 0);
        acc3 = __builtin_amdgcn_mfma_f32_16x16x32_bf16(a, b3, acc3, 0, 0, 0);
    }

    // D layout: lane holds D[row=(lane>>4)*4 + r][col=lane&15]
    float* outp = part + (size_t)ks * MM * TT;
    const int mrow = mt * MT + msub + (lane >> 4) * 4;
    const int ncol = nbase + (lane & 15);
    #pragma unroll
    for (int r = 0; r < 4; ++r) {
        const size_t base = (size_t)(mrow + r) * TT + ncol;
        outp[base +  0] = acc0[r];
        outp[base + 16] = acc1[r];
        outp[base + 32] = acc2[r];
        outp[base + 48] = acc3[r];
    }
}

// ---------------------------------------------------------------------------
// Reduce split-K partials + bias -> out. float4 per thread, 256 blocks.
// ---------------------------------------------------------------------------
__global__ __launch_bounds__(256) void reduce_kernel(
    const float* __restrict__ part,  // [KSPLIT, M*T]
    const float* __restrict__ fc_b,  // [T]
    float* __restrict__ out)         // [M*T]
{
    const int i = blockIdx.x * 256 + threadIdx.x;   // float4 index
    float4 s = *(const float4*)(fc_b + (i & 31) * 4);
    #pragma unroll
    for (int k = 0; k < KSPLIT; ++k) {
        float4 p = *(const float4*)(part + (size_t)k * MM * TT + 4 * (size_t)i);
        s.x += p.x; s.y += p.y; s.z += p.z; s.w += p.w;
    }
    *(float4*)(out + 4 * (size_t)i) = s;
}

extern "C" void kernel_launch(void* const* d_in, const int* in_sizes, int n_in,
                              void* d_out, int out_size, void* d_ws, size_t ws_size,
                              hipStream_t stream) {
    const float* hs       = (const float*)d_in[0];
    const int*   subw_idx = (const int*)  d_in[1];
    const int*   subw_cnt = (const int*)  d_in[2];
    const int*   num_ent  = (const int*)  d_in[3];
    const float* fc_w     = (const float*)d_in[4];
    const float* fc_b     = (const float*)d_in[5];
    float*       out      = (float*)d_out;
    float*       part     = (float*)d_ws;   // 8 MB partials

    fc_fused_kernel<<<(MM / MT) * KSPLIT, 256, 0, stream>>>(
        hs, subw_idx, subw_cnt, num_ent, fc_w, part);
    reduce_kernel<<<(MM * TT / 4) / 256, 256, 0, stream>>>(part, fc_b, out);
}